// Round 20
// baseline (141.359 us; speedup 1.0000x reference)
//
#include <hip/hip_runtime.h>

// NW kernel regression, double-MFMA (attention structure) — r19 skeleton
// (proven 28.9us) + fused last-block reduce epilogue:
//  - nw_reduce kernel removed; per-qg atomic counter (memset each launch);
//    each (qg,sb) block: store partials -> threadfence (release) -> atomicAdd;
//    last arriver: threadfence (acquire) -> sums all sb slices in ascending
//    order (bitwise-identical to the old reduce) -> out = num/den + 1e-6.
//   MFMA1: fidx = ssL*(|q|^2+|k|^2-2q.k)+0.5 as rank-13 f16 hi/lo GEMM
//   VALU:  w = lut16[min(fidx, LUTN)]  (fp16 NN LUT, ds_read_u16; lower clamp
//          free via HW cvt_u32 saturation)
//   MFMA2: [num|den] = W @ [V|1]  (ch8 = 1.0 denominator column)
// Conventions (proven r12/r14/r15/r17/r18/r19):
//   A-frag 32x32x16: A[row=lane&31][slot=(lane>>5)*8+j]
//   B-frag:          B[slot=(lane>>5)*8+j][col=lane&31]
//   D:               col=lane&31, row=(reg&3)+8*(reg>>2)+4*(lane>>5)
//   vfrag key perm(g,j)=(j&3)+8*(j>>2)+4*g (+16 for set b), folded in prep.

typedef _Float16 h8 __attribute__((ext_vector_type(8)));
typedef float f32x16 __attribute__((ext_vector_type(16)));
typedef float f32x4 __attribute__((ext_vector_type(4)));

#define NCH 8
#define TPB 512        // 8 waves
#define QPB 256        // 8 waves x 32 query-rows
#define KSB 512        // keys per split = 16 tiles of 32
#define NTILE (KSB / 32)
#define LUTN 4096

__device__ __forceinline__ float nw_weight_exact(float cd) {
    float r  = __builtin_amdgcn_fractf(cd);
    float sn = __builtin_amdgcn_sinf(r);
    float cs = __builtin_amdgcn_cosf(r);
    float t  = (1.0f - cd) * (1.0f / 3.0f);
    float wt = fmaf(sn, 0.15915494309189535f, fmaf(cs, t, t + t));
    return fmaxf(wt, 0.0f);
}

__device__ __forceinline__ void split16(float x, _Float16& h, _Float16& l) {
    h = (_Float16)x;
    l = (_Float16)(x - (float)h);
}

// kfrag[key*2+g][j]: A-side slots; vfrag[(tile*2+set)*64+lane]: B-side V-frags
__global__ __launch_bounds__(256) void nw_prep(const float* __restrict__ k,
                                               const float* __restrict__ v,
                                               const float* __restrict__ kl,
                                               h8* __restrict__ kfrag,
                                               h8* __restrict__ vfrag,
                                               int M) {
    const int idx = blockIdx.x * 256 + threadIdx.x;
    const float iL = 1.0f / kl[0];
    const float ssL = iL * iL * (float)LUTN;
    if (idx < M) {
        const float x = k[(size_t)idx * 3 + 0];
        const float y = k[(size_t)idx * 3 + 1];
        const float z = k[(size_t)idx * 3 + 2];
        const float cx = -2.0f * ssL * x, cy = -2.0f * ssL * y, cz = -2.0f * ssL * z;
        const float k2 = ssL * fmaf(x, x, fmaf(y, y, z * z));
        _Float16 cxh, cxl, cyh, cyl, czh, czl, k2h, k2l;
        split16(cx, cxh, cxl); split16(cy, cyh, cyl);
        split16(cz, czh, czl); split16(k2, k2h, k2l);
        h8 lo = {cxh, cxh, cxl, cyh, cyh, cyl, czh, czh};
        h8 hi = {czl, k2h, k2l, (_Float16)1.0f, (_Float16)1.0f,
                 (_Float16)0.0f, (_Float16)0.0f, (_Float16)0.0f};
        kfrag[idx * 2 + 0] = lo;
        kfrag[idx * 2 + 1] = hi;
    }
    const int nv = (M / 32) * 128;   // tiles * 2 sets * 64 lanes
    if (idx < nv) {
        const int t = idx >> 7, r = idx & 127;
        const int set = r >> 6, l = r & 63;
        const int ch = l & 31, g = l >> 5;
        h8 o;
#pragma unroll
        for (int j = 0; j < 8; ++j) {
            const int key = t * 32 + set * 16 + ((j & 3) + 8 * (j >> 2) + 4 * g);
            const float val = (ch < 8) ? v[(size_t)key * 8 + ch]
                                       : (ch == 8 ? 1.0f : 0.0f);
            o[j] = (_Float16)val;
        }
        vfrag[(size_t)(t * 2 + set) * 64 + l] = o;
    }
}

__global__ __launch_bounds__(TPB) void nw_main(const float* __restrict__ q,
                                               const h8* __restrict__ kfrag,
                                               const h8* __restrict__ vfrag,
                                               const float* __restrict__ kl,
                                               float* __restrict__ part,
                                               int* __restrict__ cnt,
                                               float* __restrict__ out,
                                               int N) {
    __shared__ _Float16 lutw16[LUTN + 2];   // 8.2 KB fp16 LUT
    __shared__ int lastflag;

    const int tid  = threadIdx.x;
    const int lane = tid & 63;
    const int wid  = tid >> 6;
    const int qg   = blockIdx.x;
    const int sb   = blockIdx.y;
    const int nsb  = gridDim.y;

    const float iL = 1.0f / kl[0];
    const float ssL = iL * iL * (float)LUTN;

    for (int e = tid; e <= LUTN; e += TPB)
        lutw16[e] = (_Float16)nw_weight_exact(
            __builtin_amdgcn_sqrtf((float)e * (1.0f / (float)LUTN)));
    __syncthreads();

    const int row = lane & 31;
    const int g   = lane >> 5;
    const int qi  = qg * QPB + wid * 32 + row;
    const float qx = q[qi * 3 + 0];
    const float qy = q[qi * 3 + 1];
    const float qz = q[qi * 3 + 2];
    const float q2 = ssL * fmaf(qx, qx, fmaf(qy, qy, qz * qz)) + 0.5f;

    _Float16 qxh, qxl, qyh, qyl, qzh, qzl, q2h, q2l;
    split16(qx, qxh, qxl); split16(qy, qyh, qyl);
    split16(qz, qzh, qzl); split16(q2, q2h, q2l);
    const _Float16 one = (_Float16)1.0f, zer = (_Float16)0.0f;
    // B-frag (constant across tiles): g=0 slots0..7, g=1 slots8..15
    h8 qf;
    qf[0] = g ? qzh : qxh;
    qf[1] = g ? one : qxl;
    qf[2] = g ? one : qxh;
    qf[3] = g ? q2h : qyh;
    qf[4] = g ? q2l : qyl;
    qf[5] = g ? zer : qyh;
    qf[6] = g ? zer : qzh;
    qf[7] = g ? zer : qzl;

    const h8* __restrict__ kfq = kfrag + (size_t)(sb * KSB) * 2;
    const h8* __restrict__ vfq = vfrag + (size_t)(sb * NTILE) * 128;

    f32x16 acc;
#pragma unroll
    for (int e = 0; e < 16; ++e) acc[e] = 0.0f;
    f32x16 zacc;
#pragma unroll
    for (int e = 0; e < 16; ++e) zacc[e] = 0.0f;

    // tile-0 operands
    h8 ka  = kfq[(size_t)row * 2 + g];
    h8 vfa = vfq[lane];
    h8 vfb = vfq[64 + lane];

    for (int t = 0; t < NTILE; ++t) {
        const int tn = (t + 1 < NTILE) ? t + 1 : t;
        const h8 ka_n  = kfq[(size_t)(tn * 32 + row) * 2 + g];
        const h8 vfa_n = vfq[(size_t)(tn * 2 + 0) * 64 + lane];
        const h8 vfb_n = vfq[(size_t)(tn * 2 + 1) * 64 + lane];

        const f32x16 s = __builtin_amdgcn_mfma_f32_32x32x16_f16(ka, qf, zacc, 0, 0, 0);

        h8 afa, afb;
#pragma unroll
        for (int r = 0; r < 8; ++r) {
            const float fx = fminf(s[r], (float)LUTN);      // lower clamp: HW cvt sat
            afa[r] = lutw16[(unsigned)fx];                  // ds_read_u16
        }
#pragma unroll
        for (int r = 0; r < 8; ++r) {
            const float fx = fminf(s[8 + r], (float)LUTN);
            afb[r] = lutw16[(unsigned)fx];
        }
        acc = __builtin_amdgcn_mfma_f32_32x32x16_f16(afa, vfa, acc, 0, 0, 0);
        acc = __builtin_amdgcn_mfma_f32_32x32x16_f16(afb, vfb, acc, 0, 0, 0);

        ka = ka_n; vfa = vfa_n; vfb = vfb_n;
    }

    // D: col=lane&31=channel, row=(reg&3)+8*(reg>>2)+4*g = local query
    const int ch = lane & 31;
    if (ch < 9) {
#pragma unroll
        for (int rq = 0; rq < 4; ++rq) {
            f32x4 o = {acc[4 * rq + 0], acc[4 * rq + 1], acc[4 * rq + 2], acc[4 * rq + 3]};
            const int gi = qg * QPB + wid * 32 + 8 * rq + 4 * g;
            *(f32x4*)(part + ((size_t)sb * 10 + ch) * N + gi) = o;
        }
    }

    // ---- fused epilogue: last block for this qg reduces all sb slices ----
    __threadfence();                 // release: partials visible device-wide
    __syncthreads();
    if (tid == 0) {
        const int old = atomicAdd(&cnt[qg], 1);
        lastflag = (old == nsb - 1);
    }
    __syncthreads();
    if (lastflag) {
        __threadfence();             // acquire: see all other blocks' partials
        if (tid < QPB) {
            const int i = qg * QPB + tid;
            float s[NCH];
#pragma unroll
            for (int c = 0; c < NCH; ++c) s[c] = 0.0f;
            float d = 0.0f;
            for (int sbb = 0; sbb < nsb; ++sbb) {   // ascending: same order as before
                const float* base = part + (size_t)sbb * 10 * N;
                d += base[8 * (size_t)N + i];
#pragma unroll
                for (int c = 0; c < NCH; ++c) s[c] += base[(size_t)c * N + i];
            }
            const float rd = 1.0f / d;
            float4* o4 = (float4*)(out + (size_t)i * NCH);
            o4[0] = make_float4(fmaf(s[0], rd, 1e-6f), fmaf(s[1], rd, 1e-6f),
                                fmaf(s[2], rd, 1e-6f), fmaf(s[3], rd, 1e-6f));
            o4[1] = make_float4(fmaf(s[4], rd, 1e-6f), fmaf(s[5], rd, 1e-6f),
                                fmaf(s[6], rd, 1e-6f), fmaf(s[7], rd, 1e-6f));
        }
    }
}

// generic fallback: one thread per query over all keys (exact math)
__global__ __launch_bounds__(256) void nw_full(const float* __restrict__ q,
                                               const float* __restrict__ k,
                                               const float* __restrict__ v,
                                               const float* __restrict__ kl,
                                               float* __restrict__ out,
                                               int N, int M) {
    const int i = blockIdx.x * 256 + threadIdx.x;
    if (i >= N) return;
    const float qx = q[i * 3 + 0], qy = q[i * 3 + 1], qz = q[i * 3 + 2];
    const float invL = 1.0f / kl[0];
    float num[NCH];
#pragma unroll
    for (int c = 0; c < NCH; ++c) num[c] = 0.0f;
    float den = 0.0f;
    for (int j = 0; j < M; ++j) {
        float dx = qx - k[j * 3 + 0], dy = qy - k[j * 3 + 1], dz = qz - k[j * 3 + 2];
        float d2 = fmaf(dx, dx, fmaf(dy, dy, dz * dz));
        float wt = nw_weight_exact(__builtin_amdgcn_sqrtf(d2) * invL);
        den += wt;
#pragma unroll
        for (int c = 0; c < NCH; ++c) num[c] = fmaf(wt, v[j * NCH + c], num[c]);
    }
    const float rden = 1.0f / den;
#pragma unroll
    for (int c = 0; c < NCH; ++c) out[i * NCH + c] = fmaf(num[c], rden, 1e-6f);
}

extern "C" void kernel_launch(void* const* d_in, const int* in_sizes, int n_in,
                              void* d_out, int out_size, void* d_ws, size_t ws_size,
                              hipStream_t stream) {
    const float* q  = (const float*)d_in[0];
    const float* k  = (const float*)d_in[1];
    const float* v  = (const float*)d_in[2];
    const float* kl = (const float*)d_in[3];
    float* out = (float*)d_out;

    const int N = in_sizes[0] / 3;   // 8192 queries
    const int M = in_sizes[1] / 3;   // 8192 keys

    const int nsb = (M + KSB - 1) / KSB;
    const int nqg = N / QPB;
    const size_t part_sz  = (size_t)nsb * 10 * N * sizeof(float);
    const size_t kfrag_sz = (size_t)M * 2 * sizeof(h8);
    const size_t vfrag_sz = (size_t)(M / 32) * 128 * sizeof(h8);
    const size_t cnt_sz   = (size_t)nqg * sizeof(int);

    if ((N % QPB) == 0 && (M % KSB) == 0 &&
        ws_size >= part_sz + kfrag_sz + vfrag_sz + cnt_sz) {
        float* part  = (float*)d_ws;
        h8*    kfrag = (h8*)((char*)d_ws + part_sz);
        h8*    vfrag = (h8*)((char*)d_ws + part_sz + kfrag_sz);
        int*   cnt   = (int*)((char*)d_ws + part_sz + kfrag_sz + vfrag_sz);
        hipMemsetAsync(cnt, 0, cnt_sz, stream);
        const int nprep = (M / 32) * 128;   // >= M
        nw_prep<<<(nprep + 255) / 256, 256, 0, stream>>>(k, v, kl, kfrag, vfrag, M);
        dim3 grid(nqg, nsb);
        nw_main<<<grid, TPB, 0, stream>>>(q, kfrag, vfrag, kl, part, cnt, out, N);
    } else {
        nw_full<<<(N + 255) / 256, 256, 0, stream>>>(q, k, v, kl, out, N, M);
    }
}

// Round 21
// 32.574 us; speedup vs baseline: 4.3397x; 4.3397x over previous
//
#include <hip/hip_runtime.h>

// NW kernel regression, double-MFMA (attention structure) — r19 skeleton
// (proven 28.9us; r20's fused-epilogue threadfence thrashed L2, reverted)
// with one change: TPB 1024 / QPB 512 -> grid 16x16 = 256 blocks = exactly
// 1 block/CU (perfect dispatch balance, 16 waves/CU, half the LUT rebuilds).
//   MFMA1: fidx = ssL*(|q|^2+|k|^2-2q.k)+0.5 as rank-13 f16 hi/lo GEMM
//   VALU:  w = lut16[min(fidx, LUTN)]  (fp16 NN LUT, ds_read_u16; lower clamp
//          free via HW cvt_u32 saturation)
//   MFMA2: [num|den] = W @ [V|1]  (ch8 = 1.0 denominator column)
// Conventions (proven r12/r14/r15/r17/r18/r19):
//   A-frag 32x32x16: A[row=lane&31][slot=(lane>>5)*8+j]
//   B-frag:          B[slot=(lane>>5)*8+j][col=lane&31]
//   D:               col=lane&31, row=(reg&3)+8*(reg>>2)+4*(lane>>5)
//   vfrag key perm(g,j)=(j&3)+8*(j>>2)+4*g (+16 for set b), folded in prep.

typedef _Float16 h8 __attribute__((ext_vector_type(8)));
typedef float f32x16 __attribute__((ext_vector_type(16)));
typedef float f32x4 __attribute__((ext_vector_type(4)));

#define NCH 8
#define TPB 1024       // 16 waves
#define QPB 512        // 16 waves x 32 query-rows
#define KSB 512        // keys per split = 16 tiles of 32
#define NTILE (KSB / 32)
#define LUTN 4096

__device__ __forceinline__ float nw_weight_exact(float cd) {
    float r  = __builtin_amdgcn_fractf(cd);
    float sn = __builtin_amdgcn_sinf(r);
    float cs = __builtin_amdgcn_cosf(r);
    float t  = (1.0f - cd) * (1.0f / 3.0f);
    float wt = fmaf(sn, 0.15915494309189535f, fmaf(cs, t, t + t));
    return fmaxf(wt, 0.0f);
}

__device__ __forceinline__ void split16(float x, _Float16& h, _Float16& l) {
    h = (_Float16)x;
    l = (_Float16)(x - (float)h);
}

// kfrag[key*2+g][j]: A-side slots; vfrag[(tile*2+set)*64+lane]: B-side V-frags
__global__ __launch_bounds__(256) void nw_prep(const float* __restrict__ k,
                                               const float* __restrict__ v,
                                               const float* __restrict__ kl,
                                               h8* __restrict__ kfrag,
                                               h8* __restrict__ vfrag,
                                               int M) {
    const int idx = blockIdx.x * 256 + threadIdx.x;
    const float iL = 1.0f / kl[0];
    const float ssL = iL * iL * (float)LUTN;
    if (idx < M) {
        const float x = k[(size_t)idx * 3 + 0];
        const float y = k[(size_t)idx * 3 + 1];
        const float z = k[(size_t)idx * 3 + 2];
        const float cx = -2.0f * ssL * x, cy = -2.0f * ssL * y, cz = -2.0f * ssL * z;
        const float k2 = ssL * fmaf(x, x, fmaf(y, y, z * z));
        _Float16 cxh, cxl, cyh, cyl, czh, czl, k2h, k2l;
        split16(cx, cxh, cxl); split16(cy, cyh, cyl);
        split16(cz, czh, czl); split16(k2, k2h, k2l);
        h8 lo = {cxh, cxh, cxl, cyh, cyh, cyl, czh, czh};
        h8 hi = {czl, k2h, k2l, (_Float16)1.0f, (_Float16)1.0f,
                 (_Float16)0.0f, (_Float16)0.0f, (_Float16)0.0f};
        kfrag[idx * 2 + 0] = lo;
        kfrag[idx * 2 + 1] = hi;
    }
    const int nv = (M / 32) * 128;   // tiles * 2 sets * 64 lanes
    if (idx < nv) {
        const int t = idx >> 7, r = idx & 127;
        const int set = r >> 6, l = r & 63;
        const int ch = l & 31, g = l >> 5;
        h8 o;
#pragma unroll
        for (int j = 0; j < 8; ++j) {
            const int key = t * 32 + set * 16 + ((j & 3) + 8 * (j >> 2) + 4 * g);
            const float val = (ch < 8) ? v[(size_t)key * 8 + ch]
                                       : (ch == 8 ? 1.0f : 0.0f);
            o[j] = (_Float16)val;
        }
        vfrag[(size_t)(t * 2 + set) * 64 + l] = o;
    }
}

__global__ __launch_bounds__(TPB) void nw_main(const float* __restrict__ q,
                                               const h8* __restrict__ kfrag,
                                               const h8* __restrict__ vfrag,
                                               const float* __restrict__ kl,
                                               float* __restrict__ part,
                                               int N) {
    __shared__ _Float16 lutw16[LUTN + 2];   // 8.2 KB fp16 LUT

    const int tid  = threadIdx.x;
    const int lane = tid & 63;
    const int wid  = tid >> 6;
    const int qg   = blockIdx.x;
    const int sb   = blockIdx.y;

    const float iL = 1.0f / kl[0];
    const float ssL = iL * iL * (float)LUTN;

    for (int e = tid; e <= LUTN; e += TPB)
        lutw16[e] = (_Float16)nw_weight_exact(
            __builtin_amdgcn_sqrtf((float)e * (1.0f / (float)LUTN)));
    __syncthreads();

    const int row = lane & 31;
    const int g   = lane >> 5;
    const int qi  = qg * QPB + wid * 32 + row;
    const float qx = q[qi * 3 + 0];
    const float qy = q[qi * 3 + 1];
    const float qz = q[qi * 3 + 2];
    const float q2 = ssL * fmaf(qx, qx, fmaf(qy, qy, qz * qz)) + 0.5f;

    _Float16 qxh, qxl, qyh, qyl, qzh, qzl, q2h, q2l;
    split16(qx, qxh, qxl); split16(qy, qyh, qyl);
    split16(qz, qzh, qzl); split16(q2, q2h, q2l);
    const _Float16 one = (_Float16)1.0f, zer = (_Float16)0.0f;
    // B-frag (constant across tiles): g=0 slots0..7, g=1 slots8..15
    h8 qf;
    qf[0] = g ? qzh : qxh;
    qf[1] = g ? one : qxl;
    qf[2] = g ? one : qxh;
    qf[3] = g ? q2h : qyh;
    qf[4] = g ? q2l : qyl;
    qf[5] = g ? zer : qyh;
    qf[6] = g ? zer : qzh;
    qf[7] = g ? zer : qzl;

    const h8* __restrict__ kfq = kfrag + (size_t)(sb * KSB) * 2;
    const h8* __restrict__ vfq = vfrag + (size_t)(sb * NTILE) * 128;

    f32x16 acc;
#pragma unroll
    for (int e = 0; e < 16; ++e) acc[e] = 0.0f;
    f32x16 zacc;
#pragma unroll
    for (int e = 0; e < 16; ++e) zacc[e] = 0.0f;

    // tile-0 operands
    h8 ka  = kfq[(size_t)row * 2 + g];
    h8 vfa = vfq[lane];
    h8 vfb = vfq[64 + lane];

    for (int t = 0; t < NTILE; ++t) {
        const int tn = (t + 1 < NTILE) ? t + 1 : t;
        const h8 ka_n  = kfq[(size_t)(tn * 32 + row) * 2 + g];
        const h8 vfa_n = vfq[(size_t)(tn * 2 + 0) * 64 + lane];
        const h8 vfb_n = vfq[(size_t)(tn * 2 + 1) * 64 + lane];

        const f32x16 s = __builtin_amdgcn_mfma_f32_32x32x16_f16(ka, qf, zacc, 0, 0, 0);

        h8 afa, afb;
#pragma unroll
        for (int r = 0; r < 8; ++r) {
            const float fx = fminf(s[r], (float)LUTN);      // lower clamp: HW cvt sat
            afa[r] = lutw16[(unsigned)fx];                  // ds_read_u16
        }
#pragma unroll
        for (int r = 0; r < 8; ++r) {
            const float fx = fminf(s[8 + r], (float)LUTN);
            afb[r] = lutw16[(unsigned)fx];
        }
        acc = __builtin_amdgcn_mfma_f32_32x32x16_f16(afa, vfa, acc, 0, 0, 0);
        acc = __builtin_amdgcn_mfma_f32_32x32x16_f16(afb, vfb, acc, 0, 0, 0);

        ka = ka_n; vfa = vfa_n; vfb = vfb_n;
    }

    // D: col=lane&31=channel, row=(reg&3)+8*(reg>>2)+4*g = local query
    const int ch = lane & 31;
    if (ch < 9) {
#pragma unroll
        for (int rq = 0; rq < 4; ++rq) {
            f32x4 o = {acc[4 * rq + 0], acc[4 * rq + 1], acc[4 * rq + 2], acc[4 * rq + 3]};
            const int gi = qg * QPB + wid * 32 + 8 * rq + 4 * g;
            *(f32x4*)(part + ((size_t)sb * 10 + ch) * N + gi) = o;
        }
    }
}

// out[i,c] = (sum_sb num) / (sum_sb den) + 1e-6
// grid: x = N/256 query-chunks, y = NCH channels; coalesced, ascending sb.
__global__ __launch_bounds__(256) void nw_reduce(const float* __restrict__ part,
                                                 float* __restrict__ out,
                                                 int N, int nsb) {
    const int i = blockIdx.x * 256 + threadIdx.x;
    const int c = blockIdx.y;
    if (i >= N) return;
    float s = 0.0f, d = 0.0f;
    for (int sb = 0; sb < nsb; ++sb) {
        const float* base = part + (size_t)sb * 10 * N;
        s += base[(size_t)c * N + i];
        d += base[8 * (size_t)N + i];
    }
    out[(size_t)i * NCH + c] = fmaf(s, 1.0f / d, 1e-6f);
}

// generic fallback: one thread per query over all keys (exact math)
__global__ __launch_bounds__(256) void nw_full(const float* __restrict__ q,
                                               const float* __restrict__ k,
                                               const float* __restrict__ v,
                                               const float* __restrict__ kl,
                                               float* __restrict__ out,
                                               int N, int M) {
    const int i = blockIdx.x * 256 + threadIdx.x;
    if (i >= N) return;
    const float qx = q[i * 3 + 0], qy = q[i * 3 + 1], qz = q[i * 3 + 2];
    const float invL = 1.0f / kl[0];
    float num[NCH];
#pragma unroll
    for (int c = 0; c < NCH; ++c) num[c] = 0.0f;
    float den = 0.0f;
    for (int j = 0; j < M; ++j) {
        float dx = qx - k[j * 3 + 0], dy = qy - k[j * 3 + 1], dz = qz - k[j * 3 + 2];
        float d2 = fmaf(dx, dx, fmaf(dy, dy, dz * dz));
        float wt = nw_weight_exact(__builtin_amdgcn_sqrtf(d2) * invL);
        den += wt;
#pragma unroll
        for (int c = 0; c < NCH; ++c) num[c] = fmaf(wt, v[j * NCH + c], num[c]);
    }
    const float rden = 1.0f / den;
#pragma unroll
    for (int c = 0; c < NCH; ++c) out[i * NCH + c] = fmaf(num[c], rden, 1e-6f);
}

extern "C" void kernel_launch(void* const* d_in, const int* in_sizes, int n_in,
                              void* d_out, int out_size, void* d_ws, size_t ws_size,
                              hipStream_t stream) {
    const float* q  = (const float*)d_in[0];
    const float* k  = (const float*)d_in[1];
    const float* v  = (const float*)d_in[2];
    const float* kl = (const float*)d_in[3];
    float* out = (float*)d_out;

    const int N = in_sizes[0] / 3;   // 8192 queries
    const int M = in_sizes[1] / 3;   // 8192 keys

    const int nsb = (M + KSB - 1) / KSB;
    const size_t part_sz  = (size_t)nsb * 10 * N * sizeof(float);
    const size_t kfrag_sz = (size_t)M * 2 * sizeof(h8);
    const size_t vfrag_sz = (size_t)(M / 32) * 128 * sizeof(h8);

    if ((N % QPB) == 0 && (M % KSB) == 0 && ws_size >= part_sz + kfrag_sz + vfrag_sz) {
        float* part  = (float*)d_ws;
        h8*    kfrag = (h8*)((char*)d_ws + part_sz);
        h8*    vfrag = (h8*)((char*)d_ws + part_sz + kfrag_sz);
        const int nprep = (M / 32) * 128;   // >= M
        nw_prep<<<(nprep + 255) / 256, 256, 0, stream>>>(k, v, kl, kfrag, vfrag, M);
        dim3 grid(N / QPB, nsb);
        nw_main<<<grid, TPB, 0, stream>>>(q, kfrag, vfrag, kl, part, N);
        dim3 rgrid((N + 255) / 256, NCH);
        nw_reduce<<<rgrid, 256, 0, stream>>>(part, out, N, nsb);
    } else {
        nw_full<<<(N + 255) / 256, 256, 0, stream>>>(q, k, v, kl, out, N, M);
    }
}

// Round 22
// 29.309 us; speedup vs baseline: 4.8231x; 1.1114x over previous
//
#include <hip/hip_runtime.h>

// NW kernel regression, double-MFMA (attention structure) — r19 skeleton
// (proven 28.9us; r20 fence-epilogue and r21 TPB-1024 both regressed, reverted)
// + software-pipelined MFMA1: s(t+1) issues before the gathers of tile t, so
// the 16 ds_read_u16 overlap with next tile's distance GEMM in the matrix pipe.
//   MFMA1: fidx = ssL*(|q|^2+|k|^2-2q.k)+0.5 as rank-13 f16 hi/lo GEMM
//   VALU:  w = lut16[min(fidx, LUTN)]  (fp16 NN LUT; lower clamp free via HW
//          cvt_u32 saturation)
//   MFMA2: [num|den] = W @ [V|1]  (ch8 = 1.0 denominator column)
// Conventions (proven r12/r14/r15/r17/r18/r19):
//   A-frag 32x32x16: A[row=lane&31][slot=(lane>>5)*8+j]
//   B-frag:          B[slot=(lane>>5)*8+j][col=lane&31]
//   D:               col=lane&31, row=(reg&3)+8*(reg>>2)+4*(lane>>5)
//   vfrag key perm(g,j)=(j&3)+8*(j>>2)+4*g (+16 for set b), folded in prep.

typedef _Float16 h8 __attribute__((ext_vector_type(8)));
typedef float f32x16 __attribute__((ext_vector_type(16)));
typedef float f32x4 __attribute__((ext_vector_type(4)));

#define NCH 8
#define TPB 512        // 8 waves
#define QPB 256        // 8 waves x 32 query-rows
#define KSB 512        // keys per split = 16 tiles of 32
#define NTILE (KSB / 32)
#define LUTN 4096

__device__ __forceinline__ float nw_weight_exact(float cd) {
    float r  = __builtin_amdgcn_fractf(cd);
    float sn = __builtin_amdgcn_sinf(r);
    float cs = __builtin_amdgcn_cosf(r);
    float t  = (1.0f - cd) * (1.0f / 3.0f);
    float wt = fmaf(sn, 0.15915494309189535f, fmaf(cs, t, t + t));
    return fmaxf(wt, 0.0f);
}

__device__ __forceinline__ void split16(float x, _Float16& h, _Float16& l) {
    h = (_Float16)x;
    l = (_Float16)(x - (float)h);
}

// kfrag[key*2+g][j]: A-side slots; vfrag[(tile*2+set)*64+lane]: B-side V-frags
__global__ __launch_bounds__(256) void nw_prep(const float* __restrict__ k,
                                               const float* __restrict__ v,
                                               const float* __restrict__ kl,
                                               h8* __restrict__ kfrag,
                                               h8* __restrict__ vfrag,
                                               int M) {
    const int idx = blockIdx.x * 256 + threadIdx.x;
    const float iL = 1.0f / kl[0];
    const float ssL = iL * iL * (float)LUTN;
    if (idx < M) {
        const float x = k[(size_t)idx * 3 + 0];
        const float y = k[(size_t)idx * 3 + 1];
        const float z = k[(size_t)idx * 3 + 2];
        const float cx = -2.0f * ssL * x, cy = -2.0f * ssL * y, cz = -2.0f * ssL * z;
        const float k2 = ssL * fmaf(x, x, fmaf(y, y, z * z));
        _Float16 cxh, cxl, cyh, cyl, czh, czl, k2h, k2l;
        split16(cx, cxh, cxl); split16(cy, cyh, cyl);
        split16(cz, czh, czl); split16(k2, k2h, k2l);
        h8 lo = {cxh, cxh, cxl, cyh, cyh, cyl, czh, czh};
        h8 hi = {czl, k2h, k2l, (_Float16)1.0f, (_Float16)1.0f,
                 (_Float16)0.0f, (_Float16)0.0f, (_Float16)0.0f};
        kfrag[idx * 2 + 0] = lo;
        kfrag[idx * 2 + 1] = hi;
    }
    const int nv = (M / 32) * 128;   // tiles * 2 sets * 64 lanes
    if (idx < nv) {
        const int t = idx >> 7, r = idx & 127;
        const int set = r >> 6, l = r & 63;
        const int ch = l & 31, g = l >> 5;
        h8 o;
#pragma unroll
        for (int j = 0; j < 8; ++j) {
            const int key = t * 32 + set * 16 + ((j & 3) + 8 * (j >> 2) + 4 * g);
            const float val = (ch < 8) ? v[(size_t)key * 8 + ch]
                                       : (ch == 8 ? 1.0f : 0.0f);
            o[j] = (_Float16)val;
        }
        vfrag[(size_t)(t * 2 + set) * 64 + l] = o;
    }
}

__global__ __launch_bounds__(TPB) void nw_main(const float* __restrict__ q,
                                               const h8* __restrict__ kfrag,
                                               const h8* __restrict__ vfrag,
                                               const float* __restrict__ kl,
                                               float* __restrict__ part,
                                               int N) {
    __shared__ _Float16 lutw16[LUTN + 2];   // 8.2 KB fp16 LUT

    const int tid  = threadIdx.x;
    const int lane = tid & 63;
    const int wid  = tid >> 6;
    const int qg   = blockIdx.x;
    const int sb   = blockIdx.y;

    const float iL = 1.0f / kl[0];
    const float ssL = iL * iL * (float)LUTN;

    for (int e = tid; e <= LUTN; e += TPB)
        lutw16[e] = (_Float16)nw_weight_exact(
            __builtin_amdgcn_sqrtf((float)e * (1.0f / (float)LUTN)));
    __syncthreads();

    const int row = lane & 31;
    const int g   = lane >> 5;
    const int qi  = qg * QPB + wid * 32 + row;
    const float qx = q[qi * 3 + 0];
    const float qy = q[qi * 3 + 1];
    const float qz = q[qi * 3 + 2];
    const float q2 = ssL * fmaf(qx, qx, fmaf(qy, qy, qz * qz)) + 0.5f;

    _Float16 qxh, qxl, qyh, qyl, qzh, qzl, q2h, q2l;
    split16(qx, qxh, qxl); split16(qy, qyh, qyl);
    split16(qz, qzh, qzl); split16(q2, q2h, q2l);
    const _Float16 one = (_Float16)1.0f, zer = (_Float16)0.0f;
    // B-frag (constant across tiles): g=0 slots0..7, g=1 slots8..15
    h8 qf;
    qf[0] = g ? qzh : qxh;
    qf[1] = g ? one : qxl;
    qf[2] = g ? one : qxh;
    qf[3] = g ? q2h : qyh;
    qf[4] = g ? q2l : qyl;
    qf[5] = g ? zer : qyh;
    qf[6] = g ? zer : qzh;
    qf[7] = g ? zer : qzl;

    const h8* __restrict__ kfq = kfrag + (size_t)(sb * KSB) * 2;
    const h8* __restrict__ vfq = vfrag + (size_t)(sb * NTILE) * 128;

    f32x16 acc;
#pragma unroll
    for (int e = 0; e < 16; ++e) acc[e] = 0.0f;
    f32x16 zacc;
#pragma unroll
    for (int e = 0; e < 16; ++e) zacc[e] = 0.0f;

    // tile-0 operands + pipelined first distance GEMM
    h8 vfa = vfq[lane];
    h8 vfb = vfq[64 + lane];
    f32x16 s_cur;
    {
        const h8 ka0 = kfq[(size_t)row * 2 + g];
        s_cur = __builtin_amdgcn_mfma_f32_32x32x16_f16(ka0, qf, zacc, 0, 0, 0);
    }

    for (int t = 0; t < NTILE; ++t) {
        const int tn = (t + 1 < NTILE) ? t + 1 : t;
        const h8 ka_n  = kfq[(size_t)(tn * 32 + row) * 2 + g];
        const h8 vfa_n = vfq[(size_t)(tn * 2 + 0) * 64 + lane];
        const h8 vfb_n = vfq[(size_t)(tn * 2 + 1) * 64 + lane];

        // next tile's distance GEMM issues BEFORE this tile's gathers -> the
        // matrix pipe works while the LDS pipe serves the random u16 reads
        const f32x16 s_next =
            __builtin_amdgcn_mfma_f32_32x32x16_f16(ka_n, qf, zacc, 0, 0, 0);

        h8 afa, afb;
#pragma unroll
        for (int r = 0; r < 8; ++r) {
            const float fx = fminf(s_cur[r], (float)LUTN);  // lower clamp: HW cvt sat
            afa[r] = lutw16[(unsigned)fx];                  // ds_read_u16
        }
#pragma unroll
        for (int r = 0; r < 8; ++r) {
            const float fx = fminf(s_cur[8 + r], (float)LUTN);
            afb[r] = lutw16[(unsigned)fx];
        }
        acc = __builtin_amdgcn_mfma_f32_32x32x16_f16(afa, vfa, acc, 0, 0, 0);
        acc = __builtin_amdgcn_mfma_f32_32x32x16_f16(afb, vfb, acc, 0, 0, 0);

        s_cur = s_next; vfa = vfa_n; vfb = vfb_n;
    }

    // D: col=lane&31=channel, row=(reg&3)+8*(reg>>2)+4*g = local query
    const int ch = lane & 31;
    if (ch < 9) {
#pragma unroll
        for (int rq = 0; rq < 4; ++rq) {
            f32x4 o = {acc[4 * rq + 0], acc[4 * rq + 1], acc[4 * rq + 2], acc[4 * rq + 3]};
            const int gi = qg * QPB + wid * 32 + 8 * rq + 4 * g;
            *(f32x4*)(part + ((size_t)sb * 10 + ch) * N + gi) = o;
        }
    }
}

// out[i,c] = (sum_sb num) / (sum_sb den) + 1e-6
// grid: x = N/256 query-chunks, y = NCH channels; coalesced, ascending sb.
__global__ __launch_bounds__(256) void nw_reduce(const float* __restrict__ part,
                                                 float* __restrict__ out,
                                                 int N, int nsb) {
    const int i = blockIdx.x * 256 + threadIdx.x;
    const int c = blockIdx.y;
    if (i >= N) return;
    float s = 0.0f, d = 0.0f;
    for (int sb = 0; sb < nsb; ++sb) {
        const float* base = part + (size_t)sb * 10 * N;
        s += base[(size_t)c * N + i];
        d += base[8 * (size_t)N + i];
    }
    out[(size_t)i * NCH + c] = fmaf(s, 1.0f / d, 1e-6f);
}

// generic fallback: one thread per query over all keys (exact math)
__global__ __launch_bounds__(256) void nw_full(const float* __restrict__ q,
                                               const float* __restrict__ k,
                                               const float* __restrict__ v,
                                               const float* __restrict__ kl,
                                               float* __restrict__ out,
                                               int N, int M) {
    const int i = blockIdx.x * 256 + threadIdx.x;
    if (i >= N) return;
    const float qx = q[i * 3 + 0], qy = q[i * 3 + 1], qz = q[i * 3 + 2];
    const float invL = 1.0f / kl[0];
    float num[NCH];
#pragma unroll
    for (int c = 0; c < NCH; ++c) num[c] = 0.0f;
    float den = 0.0f;
    for (int j = 0; j < M; ++j) {
        float dx = qx - k[j * 3 + 0], dy = qy - k[j * 3 + 1], dz = qz - k[j * 3 + 2];
        float d2 = fmaf(dx, dx, fmaf(dy, dy, dz * dz));
        float wt = nw_weight_exact(__builtin_amdgcn_sqrtf(d2) * invL);
        den += wt;
#pragma unroll
        for (int c = 0; c < NCH; ++c) num[c] = fmaf(wt, v[j * NCH + c], num[c]);
    }
    const float rden = 1.0f / den;
#pragma unroll
    for (int c = 0; c < NCH; ++c) out[i * NCH + c] = fmaf(num[c], rden, 1e-6f);
}

extern "C" void kernel_launch(void* const* d_in, const int* in_sizes, int n_in,
                              void* d_out, int out_size, void* d_ws, size_t ws_size,
                              hipStream_t stream) {
    const float* q  = (const float*)d_in[0];
    const float* k  = (const float*)d_in[1];
    const float* v  = (const float*)d_in[2];
    const float* kl = (const float*)d_in[3];
    float* out = (float*)d_out;

    const int N = in_sizes[0] / 3;   // 8192 queries
    const int M = in_sizes[1] / 3;   // 8192 keys

    const int nsb = (M + KSB - 1) / KSB;
    const size_t part_sz  = (size_t)nsb * 10 * N * sizeof(float);
    const size_t kfrag_sz = (size_t)M * 2 * sizeof(h8);
    const size_t vfrag_sz = (size_t)(M / 32) * 128 * sizeof(h8);

    if ((N % QPB) == 0 && (M % KSB) == 0 && ws_size >= part_sz + kfrag_sz + vfrag_sz) {
        float* part  = (float*)d_ws;
        h8*    kfrag = (h8*)((char*)d_ws + part_sz);
        h8*    vfrag = (h8*)((char*)d_ws + part_sz + kfrag_sz);
        const int nprep = (M / 32) * 128;   // >= M
        nw_prep<<<(nprep + 255) / 256, 256, 0, stream>>>(k, v, kl, kfrag, vfrag, M);
        dim3 grid(N / QPB, nsb);
        nw_main<<<grid, TPB, 0, stream>>>(q, kfrag, vfrag, kl, part, N);
        dim3 rgrid((N + 255) / 256, NCH);
        nw_reduce<<<rgrid, 256, 0, stream>>>(part, out, N, nsb);
    } else {
        nw_full<<<(N + 255) / 256, 256, 0, stream>>>(q, k, v, kl, out, N, M);
    }
}

// Round 23
// 28.165 us; speedup vs baseline: 5.0190x; 1.0406x over previous
//
#include <hip/hip_runtime.h>

// NW kernel regression, double-MFMA (attention structure) — r19 skeleton
// (proven 28.9us; r20 fence / r21 TPB1024 / r22 pipeline all reverted) with
// ONE isolated change: the fp16 LUT is built once in nw_prep and block-copied
// (one uint4/thread) instead of 4097 trans-chain evals per block. r16's
// apparent refutation of LUT-from-global was confounded by TPB 256 (r17).
//   MFMA1: fidx = ssL*(|q|^2+|k|^2-2q.k)+0.5 as rank-13 f16 hi/lo GEMM
//   VALU:  w = lut16[min(fidx, LUTN)]  (fp16 NN LUT; lower clamp free via HW
//          cvt_u32 saturation)
//   MFMA2: [num|den] = W @ [V|1]  (ch8 = 1.0 denominator column)
// Conventions (proven r12/r14/r15/r17/r18/r19):
//   A-frag 32x32x16: A[row=lane&31][slot=(lane>>5)*8+j]
//   B-frag:          B[slot=(lane>>5)*8+j][col=lane&31]
//   D:               col=lane&31, row=(reg&3)+8*(reg>>2)+4*(lane>>5)
//   vfrag key perm(g,j)=(j&3)+8*(j>>2)+4*g (+16 for set b), folded in prep.

typedef _Float16 h8 __attribute__((ext_vector_type(8)));
typedef float f32x16 __attribute__((ext_vector_type(16)));
typedef float f32x4 __attribute__((ext_vector_type(4)));

#define NCH 8
#define TPB 512        // 8 waves
#define QPB 256        // 8 waves x 32 query-rows
#define KSB 512        // keys per split = 16 tiles of 32
#define NTILE (KSB / 32)
#define LUTN 4096
#define LUTPAD 4104    // halves; 8208 B = 513 x uint4

__device__ __forceinline__ float nw_weight_exact(float cd) {
    float r  = __builtin_amdgcn_fractf(cd);
    float sn = __builtin_amdgcn_sinf(r);
    float cs = __builtin_amdgcn_cosf(r);
    float t  = (1.0f - cd) * (1.0f / 3.0f);
    float wt = fmaf(sn, 0.15915494309189535f, fmaf(cs, t, t + t));
    return fmaxf(wt, 0.0f);
}

__device__ __forceinline__ void split16(float x, _Float16& h, _Float16& l) {
    h = (_Float16)x;
    l = (_Float16)(x - (float)h);
}

// kfrag[key*2+g][j]: A-side slots; vfrag[(tile*2+set)*64+lane]: B-side V-frags;
// lutg: fp16 LUT (built once here, copied to LDS by every main block)
__global__ __launch_bounds__(256) void nw_prep(const float* __restrict__ k,
                                               const float* __restrict__ v,
                                               const float* __restrict__ kl,
                                               h8* __restrict__ kfrag,
                                               h8* __restrict__ vfrag,
                                               _Float16* __restrict__ lutg,
                                               int M) {
    const int idx = blockIdx.x * 256 + threadIdx.x;
    const float iL = 1.0f / kl[0];
    const float ssL = iL * iL * (float)LUTN;
    if (idx < LUTPAD) {
        lutg[idx] = (idx <= LUTN)
            ? (_Float16)nw_weight_exact(__builtin_amdgcn_sqrtf((float)idx * (1.0f / (float)LUTN)))
            : (_Float16)0.0f;
    }
    if (idx < M) {
        const float x = k[(size_t)idx * 3 + 0];
        const float y = k[(size_t)idx * 3 + 1];
        const float z = k[(size_t)idx * 3 + 2];
        const float cx = -2.0f * ssL * x, cy = -2.0f * ssL * y, cz = -2.0f * ssL * z;
        const float k2 = ssL * fmaf(x, x, fmaf(y, y, z * z));
        _Float16 cxh, cxl, cyh, cyl, czh, czl, k2h, k2l;
        split16(cx, cxh, cxl); split16(cy, cyh, cyl);
        split16(cz, czh, czl); split16(k2, k2h, k2l);
        h8 lo = {cxh, cxh, cxl, cyh, cyh, cyl, czh, czh};
        h8 hi = {czl, k2h, k2l, (_Float16)1.0f, (_Float16)1.0f,
                 (_Float16)0.0f, (_Float16)0.0f, (_Float16)0.0f};
        kfrag[idx * 2 + 0] = lo;
        kfrag[idx * 2 + 1] = hi;
    }
    const int nv = (M / 32) * 128;   // tiles * 2 sets * 64 lanes
    if (idx < nv) {
        const int t = idx >> 7, r = idx & 127;
        const int set = r >> 6, l = r & 63;
        const int ch = l & 31, g = l >> 5;
        h8 o;
#pragma unroll
        for (int j = 0; j < 8; ++j) {
            const int key = t * 32 + set * 16 + ((j & 3) + 8 * (j >> 2) + 4 * g);
            const float val = (ch < 8) ? v[(size_t)key * 8 + ch]
                                       : (ch == 8 ? 1.0f : 0.0f);
            o[j] = (_Float16)val;
        }
        vfrag[(size_t)(t * 2 + set) * 64 + l] = o;
    }
}

__global__ __launch_bounds__(TPB) void nw_main(const float* __restrict__ q,
                                               const h8* __restrict__ kfrag,
                                               const h8* __restrict__ vfrag,
                                               const _Float16* __restrict__ lutg,
                                               const float* __restrict__ kl,
                                               float* __restrict__ part,
                                               int N) {
    __shared__ _Float16 lutw16[LUTPAD];   // 8.2 KB fp16 LUT

    const int tid  = threadIdx.x;
    const int lane = tid & 63;
    const int wid  = tid >> 6;
    const int qg   = blockIdx.x;
    const int sb   = blockIdx.y;

    // stage LUT global -> LDS: 513 uint4, ~1 per thread
    {
        const uint4* g4 = (const uint4*)lutg;
        uint4* s4 = (uint4*)lutw16;
        for (int e = tid; e < LUTPAD / 8; e += TPB) s4[e] = g4[e];
    }
    __syncthreads();

    const float iL = 1.0f / kl[0];
    const float ssL = iL * iL * (float)LUTN;

    const int row = lane & 31;
    const int g   = lane >> 5;
    const int qi  = qg * QPB + wid * 32 + row;
    const float qx = q[qi * 3 + 0];
    const float qy = q[qi * 3 + 1];
    const float qz = q[qi * 3 + 2];
    const float q2 = ssL * fmaf(qx, qx, fmaf(qy, qy, qz * qz)) + 0.5f;

    _Float16 qxh, qxl, qyh, qyl, qzh, qzl, q2h, q2l;
    split16(qx, qxh, qxl); split16(qy, qyh, qyl);
    split16(qz, qzh, qzl); split16(q2, q2h, q2l);
    const _Float16 one = (_Float16)1.0f, zer = (_Float16)0.0f;
    // B-frag (constant across tiles): g=0 slots0..7, g=1 slots8..15
    h8 qf;
    qf[0] = g ? qzh : qxh;
    qf[1] = g ? one : qxl;
    qf[2] = g ? one : qxh;
    qf[3] = g ? q2h : qyh;
    qf[4] = g ? q2l : qyl;
    qf[5] = g ? zer : qyh;
    qf[6] = g ? zer : qzh;
    qf[7] = g ? zer : qzl;

    const h8* __restrict__ kfq = kfrag + (size_t)(sb * KSB) * 2;
    const h8* __restrict__ vfq = vfrag + (size_t)(sb * NTILE) * 128;

    f32x16 acc;
#pragma unroll
    for (int e = 0; e < 16; ++e) acc[e] = 0.0f;
    f32x16 zacc;
#pragma unroll
    for (int e = 0; e < 16; ++e) zacc[e] = 0.0f;

    // tile-0 operands
    h8 ka  = kfq[(size_t)row * 2 + g];
    h8 vfa = vfq[lane];
    h8 vfb = vfq[64 + lane];

    for (int t = 0; t < NTILE; ++t) {
        const int tn = (t + 1 < NTILE) ? t + 1 : t;
        const h8 ka_n  = kfq[(size_t)(tn * 32 + row) * 2 + g];
        const h8 vfa_n = vfq[(size_t)(tn * 2 + 0) * 64 + lane];
        const h8 vfb_n = vfq[(size_t)(tn * 2 + 1) * 64 + lane];

        const f32x16 s = __builtin_amdgcn_mfma_f32_32x32x16_f16(ka, qf, zacc, 0, 0, 0);

        h8 afa, afb;
#pragma unroll
        for (int r = 0; r < 8; ++r) {
            const float fx = fminf(s[r], (float)LUTN);      // lower clamp: HW cvt sat
            afa[r] = lutw16[(unsigned)fx];                  // ds_read_u16
        }
#pragma unroll
        for (int r = 0; r < 8; ++r) {
            const float fx = fminf(s[8 + r], (float)LUTN);
            afb[r] = lutw16[(unsigned)fx];
        }
        acc = __builtin_amdgcn_mfma_f32_32x32x16_f16(afa, vfa, acc, 0, 0, 0);
        acc = __builtin_amdgcn_mfma_f32_32x32x16_f16(afb, vfb, acc, 0, 0, 0);

        ka = ka_n; vfa = vfa_n; vfb = vfb_n;
    }

    // D: col=lane&31=channel, row=(reg&3)+8*(reg>>2)+4*g = local query
    const int ch = lane & 31;
    if (ch < 9) {
#pragma unroll
        for (int rq = 0; rq < 4; ++rq) {
            f32x4 o = {acc[4 * rq + 0], acc[4 * rq + 1], acc[4 * rq + 2], acc[4 * rq + 3]};
            const int gi = qg * QPB + wid * 32 + 8 * rq + 4 * g;
            *(f32x4*)(part + ((size_t)sb * 10 + ch) * N + gi) = o;
        }
    }
}

// out[i,c] = (sum_sb num) / (sum_sb den) + 1e-6
// grid: x = N/256 query-chunks, y = NCH channels; coalesced, ascending sb.
__global__ __launch_bounds__(256) void nw_reduce(const float* __restrict__ part,
                                                 float* __restrict__ out,
                                                 int N, int nsb) {
    const int i = blockIdx.x * 256 + threadIdx.x;
    const int c = blockIdx.y;
    if (i >= N) return;
    float s = 0.0f, d = 0.0f;
    for (int sb = 0; sb < nsb; ++sb) {
        const float* base = part + (size_t)sb * 10 * N;
        s += base[(size_t)c * N + i];
        d += base[8 * (size_t)N + i];
    }
    out[(size_t)i * NCH + c] = fmaf(s, 1.0f / d, 1e-6f);
}

// generic fallback: one thread per query over all keys (exact math)
__global__ __launch_bounds__(256) void nw_full(const float* __restrict__ q,
                                               const float* __restrict__ k,
                                               const float* __restrict__ v,
                                               const float* __restrict__ kl,
                                               float* __restrict__ out,
                                               int N, int M) {
    const int i = blockIdx.x * 256 + threadIdx.x;
    if (i >= N) return;
    const float qx = q[i * 3 + 0], qy = q[i * 3 + 1], qz = q[i * 3 + 2];
    const float invL = 1.0f / kl[0];
    float num[NCH];
#pragma unroll
    for (int c = 0; c < NCH; ++c) num[c] = 0.0f;
    float den = 0.0f;
    for (int j = 0; j < M; ++j) {
        float dx = qx - k[j * 3 + 0], dy = qy - k[j * 3 + 1], dz = qz - k[j * 3 + 2];
        float d2 = fmaf(dx, dx, fmaf(dy, dy, dz * dz));
        float wt = nw_weight_exact(__builtin_amdgcn_sqrtf(d2) * invL);
        den += wt;
#pragma unroll
        for (int c = 0; c < NCH; ++c) num[c] = fmaf(wt, v[j * NCH + c], num[c]);
    }
    const float rden = 1.0f / den;
#pragma unroll
    for (int c = 0; c < NCH; ++c) out[i * NCH + c] = fmaf(num[c], rden, 1e-6f);
}

extern "C" void kernel_launch(void* const* d_in, const int* in_sizes, int n_in,
                              void* d_out, int out_size, void* d_ws, size_t ws_size,
                              hipStream_t stream) {
    const float* q  = (const float*)d_in[0];
    const float* k  = (const float*)d_in[1];
    const float* v  = (const float*)d_in[2];
    const float* kl = (const float*)d_in[3];
    float* out = (float*)d_out;

    const int N = in_sizes[0] / 3;   // 8192 queries
    const int M = in_sizes[1] / 3;   // 8192 keys

    const int nsb = (M + KSB - 1) / KSB;
    const size_t part_sz  = (size_t)nsb * 10 * N * sizeof(float);
    const size_t kfrag_sz = (size_t)M * 2 * sizeof(h8);
    const size_t vfrag_sz = (size_t)(M / 32) * 128 * sizeof(h8);
    const size_t lut_sz   = (size_t)LUTPAD * sizeof(_Float16);

    if ((N % QPB) == 0 && (M % KSB) == 0 &&
        ws_size >= part_sz + kfrag_sz + vfrag_sz + lut_sz) {
        float*    part  = (float*)d_ws;
        h8*       kfrag = (h8*)((char*)d_ws + part_sz);
        h8*       vfrag = (h8*)((char*)d_ws + part_sz + kfrag_sz);
        _Float16* lutg  = (_Float16*)((char*)d_ws + part_sz + kfrag_sz + vfrag_sz);
        const int nprep = (M / 32) * 128;   // >= M, >= LUTPAD
        nw_prep<<<(nprep + 255) / 256, 256, 0, stream>>>(k, v, kl, kfrag, vfrag, lutg, M);
        dim3 grid(N / QPB, nsb);
        nw_main<<<grid, TPB, 0, stream>>>(q, kfrag, vfrag, lutg, kl, part, N);
        dim3 rgrid((N + 255) / 256, NCH);
        nw_reduce<<<rgrid, 256, 0, stream>>>(part, out, N, nsb);
    } else {
        nw_full<<<(N + 255) / 256, 256, 0, stream>>>(q, k, v, kl, out, N, M);
    }
}